// Round 10
// baseline (372.391 us; speedup 1.0000x reference)
//
#include <hip/hip_runtime.h>
#include <hip/hip_fp16.h>

#define NN 50000
#define NE 800000
#define NPART 8   // 8-way partitioned histogram: cuts atomic line ping-pong

// ======== CSR build ========
// R8 lesson: count+gemm merge regressed in BOTH orderings -> keep separate.

__global__ __launch_bounds__(256) void k_count(const int* __restrict__ dst,
                                               int* __restrict__ cnt8, int E) {
    int p = blockIdx.x & (NPART - 1);
    int e = blockIdx.x * 256 + threadIdx.x;
    if (e < E) atomicAdd(&cnt8[p * NN + dst[e]], 1);
}

// scan1: per-node total (8 coalesced stride-N reads) -> block-local
// exclusive scan. (R4: single-block scan = 123us, never again.)
__global__ __launch_bounds__(256) void k_scan1(const int* __restrict__ cnt8,
                                               int* __restrict__ rowstart,
                                               int* __restrict__ sums, int n) {
    __shared__ int s[256];
    int t = threadIdx.x, gid = blockIdx.x * 256 + t;
    int tot = 0;
    if (gid < n)
        #pragma unroll
        for (int p = 0; p < NPART; ++p) tot += cnt8[p * NN + gid];
    s[t] = tot; __syncthreads();
    for (int off = 1; off < 256; off <<= 1) {
        int x = (t >= off) ? s[t - off] : 0;
        __syncthreads();
        s[t] += x; __syncthreads();
    }
    if (gid < n) rowstart[gid] = s[t] - tot;   // block-local exclusive
    if (t == 255) sums[blockIdx.x] = s[t];
}

// scan23: add global prefix; emit per-partition row starts rs8, deg, dinv.
__global__ __launch_bounds__(256) void k_scan23(const int* __restrict__ sums,
                                                int* __restrict__ rowstart,
                                                const int* __restrict__ cnt8,
                                                int* __restrict__ rs8,
                                                int* __restrict__ deg,
                                                float* __restrict__ dinv, int n) {
    __shared__ int s[256];
    int t = threadIdx.x, b = blockIdx.x;
    s[t] = (t < b) ? sums[t] : 0;
    __syncthreads();
    for (int off = 128; off > 0; off >>= 1) {
        if (t < off) s[t] += s[t + off];
        __syncthreads();
    }
    int prefix = s[0];
    int gid = b * 256 + t;
    if (gid < n) {
        int base = rowstart[gid] + prefix;
        rowstart[gid] = base;
        int tot = 0;
        #pragma unroll
        for (int p = 0; p < NPART; ++p) {
            rs8[p * NN + gid] = base;
            int c = cnt8[p * NN + gid];
            base += c; tot += c;
        }
        deg[gid] = tot;
        dinv[gid] = rsqrtf((float)tot + 1.0f);   // deg incl. self loop
    }
}

// scatter: slot claimed via atomicSub on the partition's own count.
__global__ __launch_bounds__(256) void k_scatter(const int* __restrict__ src,
                                                 const int* __restrict__ dst,
                                                 const int* __restrict__ rs8,
                                                 int* __restrict__ cnt8,
                                                 const float* __restrict__ dinv,
                                                 int2* __restrict__ csr, int E) {
    int p = blockIdx.x & (NPART - 1);
    int e = blockIdx.x * 256 + threadIdx.x;
    if (e < E) {
        int s = src[e], d = dst[e];
        int off = atomicSub(&cnt8[p * NN + d], 1) - 1;
        int pos = rs8[p * NN + d] + off;
        float w = dinv[s] * dinv[d];
        csr[pos] = make_int2(s, __float_as_int(w));
    }
}

// ======== gemm1: T[n,64] = x[n,128] @ W1 -> fp16 (LDS W staging) ========

__global__ __launch_bounds__(256) void k_gemm1(const float* __restrict__ A,
                                               const float* __restrict__ W,
                                               __half* __restrict__ T, int n) {
    __shared__ float wlds[128 * 64];
    int tid = threadIdx.x;
    for (int i = tid; i < 128 * 64; i += 256) wlds[i] = W[i];
    __syncthreads();

    int fg = tid & 15;            // feats fg*4 .. fg*4+3
    int nslot = tid >> 4;
    int nodebase = blockIdx.x * 32 + nslot * 2;

    float4 acc[2] = {};
    #pragma unroll 4
    for (int k = 0; k < 128; k += 4) {
        float4 a[2];
        #pragma unroll
        for (int r = 0; r < 2; ++r) {
            int node = nodebase + r;
            a[r] = (node < n) ? *(const float4*)&A[node * 128 + k]
                              : float4{0.f, 0.f, 0.f, 0.f};
        }
        #pragma unroll
        for (int kk = 0; kk < 4; ++kk) {
            float4 wv = *(const float4*)&wlds[(k + kk) * 64 + fg * 4];
            #pragma unroll
            for (int r = 0; r < 2; ++r) {
                float av = (kk == 0) ? a[r].x : (kk == 1) ? a[r].y
                         : (kk == 2) ? a[r].z : a[r].w;
                acc[r].x += av * wv.x;
                acc[r].y += av * wv.y;
                acc[r].z += av * wv.z;
                acc[r].w += av * wv.w;
            }
        }
    }
    #pragma unroll
    for (int r = 0; r < 2; ++r) {
        int node = nodebase + r;
        if (node < n) {
            __half2 h[2];
            h[0] = __floats2half2_rn(acc[r].x, acc[r].y);
            h[1] = __floats2half2_rn(acc[r].z, acc[r].w);
            *(uint2*)&T[node * 64 + fg * 4] = *(uint2*)h;
        }
    }
}

// ======== fused: gather (bias_in + relu) then @W (64 x F_OUT) -> fp16 ====
// 8 nodes/block (4 waves x 2/wave), fp16 rows = 1 line, fp32 accum.
// R10: tail row-loads PREDICATED (idx<c is half-uniform -> exec-mask kills
// the load). Previously tail slots loaded row 0: +45% junk line requests
// at avg deg 16 / GB 16 (the gather is line-request-bound, not HBM-bound).
// Output row stride fixed 64 (pads F_OUT=40 rows to one aligned 128B line).

#define GB 16

template <int F_OUT>
__global__ __launch_bounds__(256) void k_fused(
    const __half* __restrict__ Tin, const int2* __restrict__ csr,
    const int* __restrict__ rowstart, const int* __restrict__ deg,
    const float* __restrict__ dinv, const float* __restrict__ bias_in,
    const float* __restrict__ W, __half* __restrict__ Tout, int n)
{
    __shared__ float wlds[64 * F_OUT];
    __shared__ float g[8 * 64];
    int tid = threadIdx.x;
    for (int i = tid; i < 64 * F_OUT; i += 256) wlds[i] = W[i];  // k-major

    int wid = tid >> 6, lane = tid & 63;
    int half = lane >> 5, fl = lane & 31;
    int slot = wid * 2 + half;
    int node = blockIdx.x * 8 + slot;
    bool valid = node < n;

    float2 acc = {0.f, 0.f};
    if (valid) {
        float di = dinv[node];
        float2 tv = __half22float2(*(const __half2*)&Tin[node * 64 + fl * 2]);
        acc.x = tv.x * di * di;                    // self loop
        acc.y = tv.y * di * di;
        int s0 = rowstart[node], c = deg[node];
        for (int j = 0; j < c; j += GB) {
            int   col[GB];
            float w[GB];
            #pragma unroll
            for (int u = 0; u < GB; ++u) {
                int idx = j + u;
                int2 cw = (idx < c) ? csr[s0 + idx] : make_int2(0, 0);
                col[u] = cw.x;
                w[u]   = __int_as_float(cw.y);
            }
            #pragma unroll
            for (int u = 0; u < GB; ++u) {
                if (j + u < c) {   // half-uniform: exec-mask, no junk load
                    float2 tf = __half22float2(
                        *(const __half2*)&Tin[col[u] * 64 + fl * 2]);
                    acc.x += w[u] * tf.x;
                    acc.y += w[u] * tf.y;
                }
            }
        }
        float2 b = *(const float2*)&bias_in[fl * 2];
        acc.x = fmaxf(acc.x + b.x, 0.f);           // relu (both fused layers)
        acc.y = fmaxf(acc.y + b.y, 0.f);
        *(float2*)&g[slot * 64 + fl * 2] = acc;
    }
    __syncthreads();    // also covers the W staging at the top

    if (valid && (fl * 2 + 1) < F_OUT) {
        float2 o = {0.f, 0.f};
        #pragma unroll 4
        for (int k = 0; k < 64; k += 4) {
            float4 gv = *(const float4*)&g[slot * 64 + k];
            #pragma unroll
            for (int kk = 0; kk < 4; ++kk) {
                float2 wv = *(const float2*)&wlds[(k + kk) * F_OUT + fl * 2];
                float gk = (kk == 0) ? gv.x : (kk == 1) ? gv.y
                         : (kk == 2) ? gv.z : gv.w;
                o.x += gk * wv.x;
                o.y += gk * wv.y;
            }
        }
        __half2 h = __floats2half2_rn(o.x, o.y);
        *(uint*)&Tout[node * 64 + fl * 2] = *(uint*)&h;   // stride 64 (padded)
    }
}

// ======== final gather: fp16 Tin (40 feats, stride 64) -> +b3 -> fp32 out =
// All lane-pairs load (padding rides in the same 128B line, never stored);
// only fl<20 store. Tail row-loads predicated as in k_fused.

__global__ __launch_bounds__(256) void k_gather_out(
    const __half* __restrict__ T, const int2* __restrict__ csr,
    const int* __restrict__ rowstart, const int* __restrict__ deg,
    const float* __restrict__ dinv, const float* __restrict__ bias,
    float* __restrict__ OUT, int n)
{
    int tid = threadIdx.x;
    int wid = tid >> 6, lane = tid & 63;
    int half = lane >> 5, fl = lane & 31;
    int node = blockIdx.x * 8 + wid * 2 + half;
    if (node >= n) return;
    int f0 = fl * 2;
    float di = dinv[node];

    float2 tv0 = __half22float2(*(const __half2*)&T[node * 64 + f0]);
    float2 acc = {tv0.x * di * di, tv0.y * di * di};

    int s0 = rowstart[node], c = deg[node];
    for (int j = 0; j < c; j += GB) {
        int   col[GB];
        float w[GB];
        #pragma unroll
        for (int u = 0; u < GB; ++u) {
            int idx = j + u;
            int2 cw = (idx < c) ? csr[s0 + idx] : make_int2(0, 0);
            col[u] = cw.x;
            w[u]   = __int_as_float(cw.y);
        }
        #pragma unroll
        for (int u = 0; u < GB; ++u) {
            if (j + u < c) {
                float2 tf = __half22float2(
                    *(const __half2*)&T[col[u] * 64 + f0]);
                acc.x += w[u] * tf.x;
                acc.y += w[u] * tf.y;
            }
        }
    }
    if (f0 + 1 < 40) {
        float2 b = *(const float2*)&bias[f0];
        *(float2*)&OUT[node * 40 + f0] = make_float2(acc.x + b.x, acc.y + b.y);
    }
}

// ---------------- launch ----------------

extern "C" void kernel_launch(void* const* d_in, const int* in_sizes, int n_in,
                              void* d_out, int out_size, void* d_ws, size_t ws_size,
                              hipStream_t stream) {
    const float* x  = (const float*)d_in[0];
    const int*   ei = (const int*)d_in[1];
    const float* W1 = (const float*)d_in[2];
    const float* b1 = (const float*)d_in[3];
    const float* W2 = (const float*)d_in[4];
    const float* b2 = (const float*)d_in[5];
    const float* W3 = (const float*)d_in[6];
    const float* b3 = (const float*)d_in[7];
    float* out = (float*)d_out;

    const int N = NN, E = NE;
    const int* src = ei;
    const int* dst = ei + E;

    // workspace (re-poisoned to 0xAA before every call)
    int*    cnt8     = (int*)d_ws;                       // NPART*N (memset 0)
    int*    rs8      = cnt8 + NPART * N;                 // NPART*N
    int*    rowstart = rs8 + NPART * N;                  // N
    int*    deg      = rowstart + N;                     // N
    float*  dinv     = (float*)(deg + N);                // N
    int*    sums     = (int*)(dinv + N);                 // 256
    int2*   csr      = (int2*)(sums + 256);              // E
    __half* tA       = (__half*)(csr + E);               // N*64 fp16
    __half* tB       = tA + (size_t)N * 64;              // N*64 fp16
    __half* tC       = tB + (size_t)N * 64;              // N*64 fp16 (40 used)

    hipMemsetAsync(cnt8, 0, sizeof(int) * NPART * N, stream);

    int eb = (E + 255) / 256;       // 3125
    int nb = (N + 255) / 256;       // 196
    int gb = (N + 31) / 32;         // 1563
    int fb = (N + 7) / 8;           // 6250

    k_count  <<<eb, 256, 0, stream>>>(dst, cnt8, E);
    k_gemm1  <<<gb, 256, 0, stream>>>(x, W1, tA, N);
    k_scan1  <<<nb, 256, 0, stream>>>(cnt8, rowstart, sums, N);
    k_scan23 <<<nb, 256, 0, stream>>>(sums, rowstart, cnt8, rs8, deg, dinv, N);
    k_scatter<<<eb, 256, 0, stream>>>(src, dst, rs8, cnt8, dinv, csr, E);

    k_fused<64><<<fb, 256, 0, stream>>>(tA, csr, rowstart, deg, dinv, b1, W2, tB, N);
    k_fused<40><<<fb, 256, 0, stream>>>(tB, csr, rowstart, deg, dinv, b2, W3, tC, N);
    k_gather_out<<<fb, 256, 0, stream>>>(tC, csr, rowstart, deg, dinv, b3, out, N);
}

// Round 11
// 320.069 us; speedup vs baseline: 1.1635x; 1.1635x over previous
//
#include <hip/hip_runtime.h>
#include <hip/hip_fp16.h>

#define NN 50000
#define NE 800000
#define NPART 8   // 8-way partitioned histogram: cuts atomic line ping-pong

// ======== CSR build ========
// R8 lesson: count+gemm merge regressed in BOTH orderings -> keep separate.

__global__ __launch_bounds__(256) void k_count(const int* __restrict__ dst,
                                               int* __restrict__ cnt8, int E) {
    int p = blockIdx.x & (NPART - 1);
    int e = blockIdx.x * 256 + threadIdx.x;
    if (e < E) atomicAdd(&cnt8[p * NN + dst[e]], 1);
}

// scan1: per-node total (8 coalesced stride-N reads) -> block-local
// exclusive scan. (R4: single-block scan = 123us, never again.)
__global__ __launch_bounds__(256) void k_scan1(const int* __restrict__ cnt8,
                                               int* __restrict__ rowstart,
                                               int* __restrict__ sums, int n) {
    __shared__ int s[256];
    int t = threadIdx.x, gid = blockIdx.x * 256 + t;
    int tot = 0;
    if (gid < n)
        #pragma unroll
        for (int p = 0; p < NPART; ++p) tot += cnt8[p * NN + gid];
    s[t] = tot; __syncthreads();
    for (int off = 1; off < 256; off <<= 1) {
        int x = (t >= off) ? s[t - off] : 0;
        __syncthreads();
        s[t] += x; __syncthreads();
    }
    if (gid < n) rowstart[gid] = s[t] - tot;   // block-local exclusive
    if (t == 255) sums[blockIdx.x] = s[t];
}

// scan23: add global prefix; emit per-partition row starts rs8, deg, dinv.
__global__ __launch_bounds__(256) void k_scan23(const int* __restrict__ sums,
                                                int* __restrict__ rowstart,
                                                const int* __restrict__ cnt8,
                                                int* __restrict__ rs8,
                                                int* __restrict__ deg,
                                                float* __restrict__ dinv, int n) {
    __shared__ int s[256];
    int t = threadIdx.x, b = blockIdx.x;
    s[t] = (t < b) ? sums[t] : 0;
    __syncthreads();
    for (int off = 128; off > 0; off >>= 1) {
        if (t < off) s[t] += s[t + off];
        __syncthreads();
    }
    int prefix = s[0];
    int gid = b * 256 + t;
    if (gid < n) {
        int base = rowstart[gid] + prefix;
        rowstart[gid] = base;
        int tot = 0;
        #pragma unroll
        for (int p = 0; p < NPART; ++p) {
            rs8[p * NN + gid] = base;
            int c = cnt8[p * NN + gid];
            base += c; tot += c;
        }
        deg[gid] = tot;
        dinv[gid] = rsqrtf((float)tot + 1.0f);   // deg incl. self loop
    }
}

// scatter: slot claimed via atomicSub on the partition's own count.
__global__ __launch_bounds__(256) void k_scatter(const int* __restrict__ src,
                                                 const int* __restrict__ dst,
                                                 const int* __restrict__ rs8,
                                                 int* __restrict__ cnt8,
                                                 const float* __restrict__ dinv,
                                                 int2* __restrict__ csr, int E) {
    int p = blockIdx.x & (NPART - 1);
    int e = blockIdx.x * 256 + threadIdx.x;
    if (e < E) {
        int s = src[e], d = dst[e];
        int off = atomicSub(&cnt8[p * NN + d], 1) - 1;
        int pos = rs8[p * NN + d] + off;
        float w = dinv[s] * dinv[d];
        csr[pos] = make_int2(s, __float_as_int(w));
    }
}

// ======== gemm1: T[n,64] = x[n,128] @ W1 -> fp16 (LDS W staging) ========

__global__ __launch_bounds__(256) void k_gemm1(const float* __restrict__ A,
                                               const float* __restrict__ W,
                                               __half* __restrict__ T, int n) {
    __shared__ float wlds[128 * 64];
    int tid = threadIdx.x;
    for (int i = tid; i < 128 * 64; i += 256) wlds[i] = W[i];
    __syncthreads();

    int fg = tid & 15;            // feats fg*4 .. fg*4+3
    int nslot = tid >> 4;
    int nodebase = blockIdx.x * 32 + nslot * 2;

    float4 acc[2] = {};
    #pragma unroll 4
    for (int k = 0; k < 128; k += 4) {
        float4 a[2];
        #pragma unroll
        for (int r = 0; r < 2; ++r) {
            int node = nodebase + r;
            a[r] = (node < n) ? *(const float4*)&A[node * 128 + k]
                              : float4{0.f, 0.f, 0.f, 0.f};
        }
        #pragma unroll
        for (int kk = 0; kk < 4; ++kk) {
            float4 wv = *(const float4*)&wlds[(k + kk) * 64 + fg * 4];
            #pragma unroll
            for (int r = 0; r < 2; ++r) {
                float av = (kk == 0) ? a[r].x : (kk == 1) ? a[r].y
                         : (kk == 2) ? a[r].z : a[r].w;
                acc[r].x += av * wv.x;
                acc[r].y += av * wv.y;
                acc[r].z += av * wv.z;
                acc[r].w += av * wv.w;
            }
        }
    }
    #pragma unroll
    for (int r = 0; r < 2; ++r) {
        int node = nodebase + r;
        if (node < n) {
            __half2 h[2];
            h[0] = __floats2half2_rn(acc[r].x, acc[r].y);
            h[1] = __floats2half2_rn(acc[r].z, acc[r].w);
            *(uint2*)&T[node * 64 + fg * 4] = *(uint2*)h;
        }
    }
}

// ======== fused: gather (bias_in + relu) then @W (64 x F_OUT) -> fp16 ====
// 8 nodes/block (4 waves x 2/wave), fp16 rows = 1 line, fp32 accum.
// R11: the gather was never actually batched in the ISA — VGPR_Count=32
// proves the allocator collapsed the 16-wide batch into a serial
// csr->row->fma chain (why GB/ILP changes R2..R9 were all neutral).
// sched_barrier(0) fences pin the 3 phases (csr loads | row loads | FMAs);
// launch_bounds(256,4) gives the allocator 128 VGPRs to hold the batch.
// Tail slots load row 0 unpredicated (L1-hot, free — R10 predication
// regressed 55->72us by destroying the batch).

#define GB 16

template <int F_OUT>
__global__ __launch_bounds__(256, 4) void k_fused(
    const __half* __restrict__ Tin, const int2* __restrict__ csr,
    const int* __restrict__ rowstart, const int* __restrict__ deg,
    const float* __restrict__ dinv, const float* __restrict__ bias_in,
    const float* __restrict__ W, __half* __restrict__ Tout, int n)
{
    __shared__ float wlds[64 * F_OUT];
    __shared__ float g[8 * 64];
    int tid = threadIdx.x;
    for (int i = tid; i < 64 * F_OUT; i += 256) wlds[i] = W[i];  // k-major

    int wid = tid >> 6, lane = tid & 63;
    int half = lane >> 5, fl = lane & 31;
    int slot = wid * 2 + half;
    int node = blockIdx.x * 8 + slot;
    bool valid = node < n;

    float2 acc = {0.f, 0.f};
    if (valid) {
        float di = dinv[node];
        float2 tv = __half22float2(*(const __half2*)&Tin[node * 64 + fl * 2]);
        acc.x = tv.x * di * di;                    // self loop
        acc.y = tv.y * di * di;
        int s0 = rowstart[node], c = deg[node];
        for (int j = 0; j < c; j += GB) {
            int   col[GB];
            float w[GB];
            #pragma unroll
            for (int u = 0; u < GB; ++u) {
                int idx = j + u;
                int2 cw = (idx < c) ? csr[s0 + idx] : make_int2(0, 0);
                col[u] = cw.x;
                w[u]   = __int_as_float(cw.y);   // 0 bits == 0.0f for tail
            }
            __builtin_amdgcn_sched_barrier(0);   // all csr loads issued above
            __half2 tv2[GB];
            #pragma unroll
            for (int u = 0; u < GB; ++u)
                tv2[u] = *(const __half2*)&Tin[col[u] * 64 + fl * 2];
            __builtin_amdgcn_sched_barrier(0);   // all row loads in flight
            #pragma unroll
            for (int u = 0; u < GB; ++u) {       // consume in issue order
                float2 tf = __half22float2(tv2[u]);
                acc.x += w[u] * tf.x;
                acc.y += w[u] * tf.y;
            }
        }
        float2 b = *(const float2*)&bias_in[fl * 2];
        acc.x = fmaxf(acc.x + b.x, 0.f);           // relu (both fused layers)
        acc.y = fmaxf(acc.y + b.y, 0.f);
        *(float2*)&g[slot * 64 + fl * 2] = acc;
    }
    __syncthreads();    // also covers the W staging at the top

    if (valid && (fl * 2 + 1) < F_OUT) {
        float2 o = {0.f, 0.f};
        #pragma unroll 4
        for (int k = 0; k < 64; k += 4) {
            float4 gv = *(const float4*)&g[slot * 64 + k];
            #pragma unroll
            for (int kk = 0; kk < 4; ++kk) {
                float2 wv = *(const float2*)&wlds[(k + kk) * F_OUT + fl * 2];
                float gk = (kk == 0) ? gv.x : (kk == 1) ? gv.y
                         : (kk == 2) ? gv.z : gv.w;
                o.x += gk * wv.x;
                o.y += gk * wv.y;
            }
        }
        __half2 h = __floats2half2_rn(o.x, o.y);
        *(uint*)&Tout[node * 64 + fl * 2] = *(uint*)&h;   // stride 64 (padded)
    }
}

// ======== final gather: fp16 Tin (40 feats, stride 64) -> +b3 -> fp32 out =
// Rows padded to one aligned 128B line: all lane-pairs load unconditionally,
// only fl<20 store. Same 3-phase fenced batch as k_fused.

__global__ __launch_bounds__(256, 4) void k_gather_out(
    const __half* __restrict__ T, const int2* __restrict__ csr,
    const int* __restrict__ rowstart, const int* __restrict__ deg,
    const float* __restrict__ dinv, const float* __restrict__ bias,
    float* __restrict__ OUT, int n)
{
    int tid = threadIdx.x;
    int wid = tid >> 6, lane = tid & 63;
    int half = lane >> 5, fl = lane & 31;
    int node = blockIdx.x * 8 + wid * 2 + half;
    if (node >= n) return;
    int f0 = fl * 2;
    float di = dinv[node];

    float2 tv0 = __half22float2(*(const __half2*)&T[node * 64 + f0]);
    float2 acc = {tv0.x * di * di, tv0.y * di * di};

    int s0 = rowstart[node], c = deg[node];
    for (int j = 0; j < c; j += GB) {
        int   col[GB];
        float w[GB];
        #pragma unroll
        for (int u = 0; u < GB; ++u) {
            int idx = j + u;
            int2 cw = (idx < c) ? csr[s0 + idx] : make_int2(0, 0);
            col[u] = cw.x;
            w[u]   = __int_as_float(cw.y);
        }
        __builtin_amdgcn_sched_barrier(0);
        __half2 tv[GB];
        #pragma unroll
        for (int u = 0; u < GB; ++u)
            tv[u] = *(const __half2*)&T[col[u] * 64 + f0];
        __builtin_amdgcn_sched_barrier(0);
        #pragma unroll
        for (int u = 0; u < GB; ++u) {
            float2 tf = __half22float2(tv[u]);
            acc.x += w[u] * tf.x;
            acc.y += w[u] * tf.y;
        }
    }
    if (f0 + 1 < 40) {
        float2 b = *(const float2*)&bias[f0];
        *(float2*)&OUT[node * 40 + f0] = make_float2(acc.x + b.x, acc.y + b.y);
    }
}

// ---------------- launch ----------------

extern "C" void kernel_launch(void* const* d_in, const int* in_sizes, int n_in,
                              void* d_out, int out_size, void* d_ws, size_t ws_size,
                              hipStream_t stream) {
    const float* x  = (const float*)d_in[0];
    const int*   ei = (const int*)d_in[1];
    const float* W1 = (const float*)d_in[2];
    const float* b1 = (const float*)d_in[3];
    const float* W2 = (const float*)d_in[4];
    const float* b2 = (const float*)d_in[5];
    const float* W3 = (const float*)d_in[6];
    const float* b3 = (const float*)d_in[7];
    float* out = (float*)d_out;

    const int N = NN, E = NE;
    const int* src = ei;
    const int* dst = ei + E;

    // workspace (re-poisoned to 0xAA before every call)
    int*    cnt8     = (int*)d_ws;                       // NPART*N (memset 0)
    int*    rs8      = cnt8 + NPART * N;                 // NPART*N
    int*    rowstart = rs8 + NPART * N;                  // N
    int*    deg      = rowstart + N;                     // N
    float*  dinv     = (float*)(deg + N);                // N
    int*    sums     = (int*)(dinv + N);                 // 256
    int2*   csr      = (int2*)(sums + 256);              // E
    __half* tA       = (__half*)(csr + E);               // N*64 fp16
    __half* tB       = tA + (size_t)N * 64;              // N*64 fp16
    __half* tC       = tB + (size_t)N * 64;              // N*64 fp16 (40 used)

    hipMemsetAsync(cnt8, 0, sizeof(int) * NPART * N, stream);

    int eb = (E + 255) / 256;       // 3125
    int nb = (N + 255) / 256;       // 196
    int gb = (N + 31) / 32;         // 1563
    int fb = (N + 7) / 8;           // 6250

    k_count  <<<eb, 256, 0, stream>>>(dst, cnt8, E);
    k_gemm1  <<<gb, 256, 0, stream>>>(x, W1, tA, N);
    k_scan1  <<<nb, 256, 0, stream>>>(cnt8, rowstart, sums, N);
    k_scan23 <<<nb, 256, 0, stream>>>(sums, rowstart, cnt8, rs8, deg, dinv, N);
    k_scatter<<<eb, 256, 0, stream>>>(src, dst, rs8, cnt8, dinv, csr, E);

    k_fused<64><<<fb, 256, 0, stream>>>(tA, csr, rowstart, deg, dinv, b1, W2, tB, N);
    k_fused<40><<<fb, 256, 0, stream>>>(tB, csr, rowstart, deg, dinv, b2, W3, tC, N);
    k_gather_out<<<fb, 256, 0, stream>>>(tC, csr, rowstart, deg, dinv, b3, out, N);
}